// Round 1
// baseline (1819.391 us; speedup 1.0000x reference)
//
#include <hip/hip_runtime.h>
#include <math.h>

// AnomalyTransformer forward, fp32 reference-accurate implementation.
// B=8, WIN=512, C_IN=C_OUT=38, D=512, H=8, EH=64, L=3, FF=512.
// d_out layout (f32): out[155648] | series[3*16777216] | prior[...] | sigma[...]
// Scores/softmax P live directly in the series region of d_out.

#define NROWS 4096  // B*WIN

// ---------------- embed: wrap-pad conv1d(k=3) + sinusoidal PE ----------------
__global__ __launch_bounds__(512) void embed_kernel(const float* __restrict__ x,
                                                    const float* __restrict__ ck,
                                                    float* __restrict__ h) {
  int bt = blockIdx.x;
  int b = bt >> 9, t = bt & 511;
  int co = threadIdx.x;
  __shared__ float xs[3][38];
  if (co < 114) {
    int w = co / 38, ci = co - w * 38;
    int r = (t - 1 + w + 512) & 511;  // wrap pad
    xs[w][ci] = x[((long)(b << 9) + r) * 38 + ci];
  }
  __syncthreads();
  float acc = 0.f;
#pragma unroll
  for (int w = 0; w < 3; ++w)
#pragma unroll
    for (int ci = 0; ci < 38; ++ci)
      acc = fmaf(xs[w][ci], ck[(w * 38 + ci) * 512 + co], acc);
  // positional embedding: even d -> sin, odd d -> cos, freq from floor(d/2)*2
  float div = expf((float)(co & ~1) * (-9.210340371976184f / 512.f));
  float ang = (float)t * div;
  float pe = (co & 1) ? cosf(ang) : sinf(ang);
  h[(long)bt * 512 + co] = acc + pe;
}

// ---------------- generic fp32 GEMM: C = alpha*A@B(+bias)(+gelu) ----------------
// Tile 64x64, BK=16, 256 threads, 4x4 micro-tile. Batched via blockIdx.z with
// z1 = z / bdiv, z2 = z % bdiv and per-operand strides. TRANSB: B_eff[k][n] = B[n*ldb+k].
template <bool GELU, bool TRANSB>
__global__ __launch_bounds__(256) void gemm_f32(
    const float* __restrict__ A, int lda, long sA1, long sA2,
    const float* __restrict__ B, int ldb, long sB1, long sB2,
    const float* __restrict__ bias,
    float* __restrict__ C, int ldc, long sC1, long sC2,
    int K, int bdiv, float alpha) {
  int z = blockIdx.z;
  int z1 = z / bdiv, z2 = z - z1 * bdiv;
  A += (long)z1 * sA1 + (long)z2 * sA2;
  B += (long)z1 * sB1 + (long)z2 * sB2;
  C += (long)z1 * sC1 + (long)z2 * sC2;

  __shared__ float As[16][68];  // As[k][m], pad 4 keeps 16B alignment
  __shared__ float Bs[16][68];  // Bs[k][n]
  int tid = threadIdx.x;
  int tx = tid & 15, ty = tid >> 4;
  int m0 = blockIdx.y * 64, n0 = blockIdx.x * 64;
  float acc[4][4] = {};
  int ml = tid >> 2, kq = (tid & 3) * 4;

  for (int k0 = 0; k0 < K; k0 += 16) {
    float4 av = *(const float4*)&A[(long)(m0 + ml) * lda + k0 + kq];
    As[kq + 0][ml] = av.x; As[kq + 1][ml] = av.y;
    As[kq + 2][ml] = av.z; As[kq + 3][ml] = av.w;
    if (!TRANSB) {
      int r = tid >> 4, c = (tid & 15) * 4;
      float4 bvv = *(const float4*)&B[(long)(k0 + r) * ldb + n0 + c];
      *(float4*)&Bs[r][c] = bvv;
    } else {
      float4 bvv = *(const float4*)&B[(long)(n0 + ml) * ldb + k0 + kq];
      Bs[kq + 0][ml] = bvv.x; Bs[kq + 1][ml] = bvv.y;
      Bs[kq + 2][ml] = bvv.z; Bs[kq + 3][ml] = bvv.w;
    }
    __syncthreads();
#pragma unroll
    for (int kk = 0; kk < 16; ++kk) {
      float4 a4 = *(const float4*)&As[kk][ty * 4];
      float4 b4 = *(const float4*)&Bs[kk][tx * 4];
      float ar[4] = {a4.x, a4.y, a4.z, a4.w};
      float br[4] = {b4.x, b4.y, b4.z, b4.w};
#pragma unroll
      for (int i = 0; i < 4; ++i)
#pragma unroll
        for (int j = 0; j < 4; ++j)
          acc[i][j] = fmaf(ar[i], br[j], acc[i][j]);
    }
    __syncthreads();
  }

  float bias4[4] = {0.f, 0.f, 0.f, 0.f};
  if (bias) {
#pragma unroll
    for (int j = 0; j < 4; ++j) bias4[j] = bias[n0 + tx * 4 + j];
  }
#pragma unroll
  for (int i = 0; i < 4; ++i) {
    float t0[4];
#pragma unroll
    for (int j = 0; j < 4; ++j) {
      float v = acc[i][j] * alpha + bias4[j];
      if (GELU) v = 0.5f * v * (1.f + erff(v * 0.7071067811865476f));
      t0[j] = v;
    }
    float4 o = {t0[0], t0[1], t0[2], t0[3]};
    *(float4*)&C[(long)(m0 + ty * 4 + i) * ldc + n0 + tx * 4] = o;
  }
}

// ---------------- softmax over rows of 512, in place (wave per row) ----------------
__global__ __launch_bounds__(256) void softmax_kernel(float* __restrict__ P) {
  long row = (long)blockIdx.x * 4 + (threadIdx.x >> 6);
  int lane = threadIdx.x & 63;
  float* p = P + row * 512 + lane * 8;
  float4 v0 = *(float4*)p;
  float4 v1 = *(float4*)(p + 4);
  float m = fmaxf(fmaxf(fmaxf(v0.x, v0.y), fmaxf(v0.z, v0.w)),
                  fmaxf(fmaxf(v1.x, v1.y), fmaxf(v1.z, v1.w)));
#pragma unroll
  for (int off = 1; off < 64; off <<= 1) m = fmaxf(m, __shfl_xor(m, off));
  v0.x = __expf(v0.x - m); v0.y = __expf(v0.y - m);
  v0.z = __expf(v0.z - m); v0.w = __expf(v0.w - m);
  v1.x = __expf(v1.x - m); v1.y = __expf(v1.y - m);
  v1.z = __expf(v1.z - m); v1.w = __expf(v1.w - m);
  float s = v0.x + v0.y + v0.z + v0.w + v1.x + v1.y + v1.z + v1.w;
#pragma unroll
  for (int off = 1; off < 64; off <<= 1) s += __shfl_xor(s, off);
  float inv = 1.f / s;
  v0.x *= inv; v0.y *= inv; v0.z *= inv; v0.w *= inv;
  v1.x *= inv; v1.y *= inv; v1.z *= inv; v1.w *= inv;
  *(float4*)p = v0;
  *(float4*)(p + 4) = v1;
}

// ---------------- prior + sigma elementwise ----------------
__global__ __launch_bounds__(256) void prior_kernel(const float* __restrict__ sig,
                                                    float* __restrict__ prior,
                                                    float* __restrict__ sigma4) {
  int blk = blockIdx.x;         // (b*8+h)*512 + i
  int i = blk & 511;
  int bh = blk >> 9;
  int b = bh >> 3, hh = bh & 7;
  float xv = sig[(((long)b << 9) + i) * 8 + hh];
  float s = 1.f / (1.f + expf(-5.f * xv)) + 1e-5f;
  float sg = expm1f(s * 1.0986122886681098f);  // 3^s - 1, accurate near 0
  float inv = 0.3989422804014327f / sg;        // 1/sqrt(2pi) / sg
  float rinv = 1.f / sg;
  long base = ((long)bh << 18) + ((long)i << 9);
  int j0 = threadIdx.x * 2;
  float d0 = fabsf((float)(i - j0));
  float d1 = fabsf((float)(i - (j0 + 1)));
  float r0 = d0 * rinv, r1 = d1 * rinv;
  float2 pv = {inv * expf(-0.5f * r0 * r0), inv * expf(-0.5f * r1 * r1)};
  float2 sv = {sg, sg};
  *(float2*)&prior[base + j0] = pv;
  *(float2*)&sigma4[base + j0] = sv;
}

// ---------------- residual + layernorm (block per row of 512) ----------------
__global__ __launch_bounds__(256) void ln_kernel(const float* __restrict__ x,
                                                 const float* __restrict__ delta,
                                                 const float* __restrict__ g,
                                                 const float* __restrict__ bb,
                                                 float* __restrict__ out) {
  long row = blockIdx.x;
  int tid = threadIdx.x;
  int c = tid * 2;
  float2 xv = *(const float2*)&x[row * 512 + c];
  if (delta) {
    float2 dv = *(const float2*)&delta[row * 512 + c];
    xv.x += dv.x; xv.y += dv.y;
  }
  float s = xv.x + xv.y;
  float q = xv.x * xv.x + xv.y * xv.y;
#pragma unroll
  for (int off = 1; off < 64; off <<= 1) {
    s += __shfl_xor(s, off);
    q += __shfl_xor(q, off);
  }
  __shared__ float red[8];
  int wid = tid >> 6;
  if ((tid & 63) == 0) { red[wid] = s; red[wid + 4] = q; }
  __syncthreads();
  float S = red[0] + red[1] + red[2] + red[3];
  float Q = red[4] + red[5] + red[6] + red[7];
  float mean = S * (1.f / 512.f);
  float var = Q * (1.f / 512.f) - mean * mean;
  float rstd = rsqrtf(var + 1e-3f);
  float2 o;
  o.x = (xv.x - mean) * rstd * g[c] + bb[c];
  o.y = (xv.y - mean) * rstd * g[c + 1] + bb[c + 1];
  *(float2*)&out[row * 512 + c] = o;
}

// ---------------- small-N GEMM (wave per row): C[row, 0..NOUT) = A[row,:]@W + bias ----------------
template <int NOUT>
__global__ __launch_bounds__(256) void gemm_smallN(const float* __restrict__ A,
                                                   const float* __restrict__ W,
                                                   const float* __restrict__ bias,
                                                   float* __restrict__ C) {
  long row = (long)blockIdx.x * 4 + (threadIdx.x >> 6);
  int lane = threadIdx.x & 63;
  float acc[NOUT];
#pragma unroll
  for (int j = 0; j < NOUT; ++j) acc[j] = 0.f;
  for (int k = lane; k < 512; k += 64) {
    float a = A[row * 512 + k];
    const float* wr = W + (long)k * NOUT;
#pragma unroll
    for (int j = 0; j < NOUT; ++j) acc[j] = fmaf(a, wr[j], acc[j]);
  }
#pragma unroll
  for (int j = 0; j < NOUT; ++j)
#pragma unroll
    for (int off = 32; off; off >>= 1) acc[j] += __shfl_xor(acc[j], off);
  if (lane == 0) {
#pragma unroll
    for (int j = 0; j < NOUT; ++j) C[row * NOUT + j] = acc[j] + bias[j];
  }
}

extern "C" void kernel_launch(void* const* d_in, const int* in_sizes, int n_in,
                              void* d_out, int out_size, void* d_ws, size_t ws_size,
                              hipStream_t stream) {
  (void)in_sizes; (void)n_in; (void)out_size; (void)ws_size;
  const float* x    = (const float*)d_in[0];
  const float* ck   = (const float*)d_in[1];
  const float* Wq   = (const float*)d_in[2];
  const float* bq   = (const float*)d_in[3];
  const float* Wk   = (const float*)d_in[4];
  const float* bk   = (const float*)d_in[5];
  const float* Wv   = (const float*)d_in[6];
  const float* bv   = (const float*)d_in[7];
  const float* Wsw  = (const float*)d_in[8];
  const float* bsw  = (const float*)d_in[9];
  const float* Wo   = (const float*)d_in[10];
  const float* bo   = (const float*)d_in[11];
  const float* W1   = (const float*)d_in[12];
  const float* b1   = (const float*)d_in[13];
  const float* W2   = (const float*)d_in[14];
  const float* b2   = (const float*)d_in[15];
  const float* ln1g = (const float*)d_in[16];
  const float* ln1b = (const float*)d_in[17];
  const float* ln2g = (const float*)d_in[18];
  const float* ln2b = (const float*)d_in[19];
  const float* lnfg = (const float*)d_in[20];
  const float* lnfb = (const float*)d_in[21];
  const float* Wp   = (const float*)d_in[22];
  const float* bp   = (const float*)d_in[23];
  float* out = (float*)d_out;

  // workspace (floats): h, q, k, v, t1, t2 each 4096*512; sig 4096*8
  float* h  = (float*)d_ws;
  float* qb = h  + 2097152;
  float* kb = qb + 2097152;
  float* vb = kb + 2097152;
  float* t1 = vb + 2097152;
  float* t2 = t1 + 2097152;
  float* sg = t2 + 2097152;

  float* series0 = out + 155648;
  float* prior0  = out + 50487296;
  float* sigma0  = out + 100818944;

  embed_kernel<<<4096, 512, 0, stream>>>(x, ck, h);

  dim3 gFull(8, 64, 1);   // N=512, M=4096
  dim3 gScore(8, 8, 64);  // N=512, M=512, z=(b,h)
  dim3 gAttn(1, 8, 64);   // N=64,  M=512, z=(b,h)

  for (int l = 0; l < 3; ++l) {
    const float* Wq_l = Wq + (long)l * 262144;  const float* bq_l = bq + (long)l * 512;
    const float* Wk_l = Wk + (long)l * 262144;  const float* bk_l = bk + (long)l * 512;
    const float* Wv_l = Wv + (long)l * 262144;  const float* bv_l = bv + (long)l * 512;
    const float* Ws_l = Wsw + (long)l * 4096;   const float* bs_l = bsw + (long)l * 8;
    const float* Wo_l = Wo + (long)l * 262144;  const float* bo_l = bo + (long)l * 512;
    const float* W1_l = W1 + (long)l * 262144;  const float* b1_l = b1 + (long)l * 512;
    const float* W2_l = W2 + (long)l * 262144;  const float* b2_l = b2 + (long)l * 512;
    float* ser = series0 + (long)l * 16777216;
    float* pri = prior0  + (long)l * 16777216;
    float* sgm = sigma0  + (long)l * 16777216;

    // Q, K, V projections
    gemm_f32<false, false><<<gFull, 256, 0, stream>>>(
        h, 512, 0, 0, Wq_l, 512, 0, 0, bq_l, qb, 512, 0, 0, 512, 1, 1.f);
    gemm_f32<false, false><<<gFull, 256, 0, stream>>>(
        h, 512, 0, 0, Wk_l, 512, 0, 0, bk_l, kb, 512, 0, 0, 512, 1, 1.f);
    gemm_f32<false, false><<<gFull, 256, 0, stream>>>(
        h, 512, 0, 0, Wv_l, 512, 0, 0, bv_l, vb, 512, 0, 0, 512, 1, 1.f);
    // sigma logits
    gemm_smallN<8><<<1024, 256, 0, stream>>>(h, Ws_l, bs_l, sg);
    // scores = scale * Q @ K^T  -> series region
    gemm_f32<false, true><<<gScore, 256, 0, stream>>>(
        qb, 512, 262144, 64, kb, 512, 262144, 64, nullptr,
        ser, 512, 2097152, 262144, 64, 8, 0.125f);
    // softmax rows in place
    softmax_kernel<<<8192, 256, 0, stream>>>(ser);
    // prior + sigma outputs
    prior_kernel<<<32768, 256, 0, stream>>>(sg, pri, sgm);
    // attn_out = P @ V
    gemm_f32<false, false><<<gAttn, 256, 0, stream>>>(
        ser, 512, 2097152, 262144, vb, 512, 262144, 64, nullptr,
        t1, 512, 262144, 64, 512, 8, 1.f);
    // Wo projection
    gemm_f32<false, false><<<gFull, 256, 0, stream>>>(
        t1, 512, 0, 0, Wo_l, 512, 0, 0, bo_l, t2, 512, 0, 0, 512, 1, 1.f);
    // h = LN(h + t2)
    ln_kernel<<<4096, 256, 0, stream>>>(h, t2, ln1g + l * 512, ln1b + l * 512, h);
    // FF
    gemm_f32<true, false><<<gFull, 256, 0, stream>>>(
        h, 512, 0, 0, W1_l, 512, 0, 0, b1_l, t1, 512, 0, 0, 512, 1, 1.f);
    gemm_f32<false, false><<<gFull, 256, 0, stream>>>(
        t1, 512, 0, 0, W2_l, 512, 0, 0, b2_l, t2, 512, 0, 0, 512, 1, 1.f);
    ln_kernel<<<4096, 256, 0, stream>>>(h, t2, ln2g + l * 512, ln2b + l * 512, h);
  }

  // final LN + projection
  ln_kernel<<<4096, 256, 0, stream>>>(h, nullptr, lnfg, lnfb, t1);
  gemm_smallN<38><<<1024, 256, 0, stream>>>(t1, Wp, bp, out);
}

// Round 2
// 1244.415 us; speedup vs baseline: 1.4620x; 1.4620x over previous
//
#include <hip/hip_runtime.h>
#include <math.h>

// AnomalyTransformer forward. bf16-MFMA GEMMs (fp32 accumulate), fp32 elsewhere.
// B=8, WIN=512, D=512, H=8, EH=64, L=3, FF=512.
// d_out (f32): out[155648] | series[3*16777216] | prior | sigma
// sigma-logit GEMM kept fp32 (prior output is 4.6x-sensitive to it).

typedef unsigned short ushort;
typedef __attribute__((ext_vector_type(8))) ushort ushort8;
typedef __attribute__((ext_vector_type(8))) short short8;
typedef __attribute__((ext_vector_type(4))) float float4v;

__device__ inline ushort f2bf(float f) {
  union { float f; unsigned u; } v; v.f = f;
  return (ushort)((v.u + 0x7fffu + ((v.u >> 16) & 1u)) >> 16);
}

// ---------------- embed: wrap-pad conv1d(k=3) + sinusoidal PE ----------------
__global__ __launch_bounds__(512) void embed_kernel(const float* __restrict__ x,
                                                    const float* __restrict__ ck,
                                                    float* __restrict__ h) {
  int bt = blockIdx.x;
  int b = bt >> 9, t = bt & 511;
  int co = threadIdx.x;
  __shared__ float xs[3][38];
  if (co < 114) {
    int w = co / 38, ci = co - w * 38;
    int r = (t - 1 + w + 512) & 511;
    xs[w][ci] = x[((long)(b << 9) + r) * 38 + ci];
  }
  __syncthreads();
  float acc = 0.f;
#pragma unroll
  for (int w = 0; w < 3; ++w)
#pragma unroll
    for (int ci = 0; ci < 38; ++ci)
      acc = fmaf(xs[w][ci], ck[(w * 38 + ci) * 512 + co], acc);
  float div = expf((float)(co & ~1) * (-9.210340371976184f / 512.f));
  float ang = (float)t * div;
  float pe = (co & 1) ? cosf(ang) : sinf(ang);
  h[(long)bt * 512 + co] = acc + pe;
}

// ---------------- weight convert+transpose: fp32 [k][n] -> bf16 [n][k], 3 layers ----------------
__global__ __launch_bounds__(256) void wcvt_kernel(const float* __restrict__ W,
                                                   ushort* __restrict__ Wt) {
  int l = blockIdx.z;
  int n = blockIdx.x * 256 + threadIdx.x;
  int k0 = blockIdx.y * 8;
  const float* w = W + (long)l * 262144;
  ushort* o = Wt + (long)l * 262144;
  ushort8 v;
#pragma unroll
  for (int i = 0; i < 8; ++i) v[i] = f2bf(w[(long)(k0 + i) * 512 + n]);
  *(ushort8*)&o[(long)n * 512 + k0] = v;
}

// ---------------- bf16 MFMA GEMM: C = alpha*(A@B) (+bias)(+gelu) ----------------
// Tile 64x64, BK=32, 256 threads (4 waves, 2x2 16x16 frags each).
// A: fp32 [m][k] (converted in staging) or bf16 [m][k] (ABF16).
// B: bf16 [n][k] (N-major, natural for transposed weights / K-matrix), or
//    bf16 [k][n] (BKMAJOR, LDS-transposed in staging; used for V).
// C: fp32 or bf16 (CBF16). Batched via z = z1*bdiv' ... z1=z/bdiv, z2=z%bdiv.
template <bool ABF16, bool BKMAJOR, bool GELU_, bool CBF16>
__global__ __launch_bounds__(256) void gemm_mfma(
    const void* __restrict__ Av, int lda, long sA1, long sA2,
    const ushort* __restrict__ B, int ldb, long sB1, long sB2,
    const float* __restrict__ bias,
    void* __restrict__ Cv, int ldc, long sC1, long sC2,
    int K, int bdiv, float alpha) {
  int z = blockIdx.z;
  int z1 = z / bdiv, z2 = z - z1 * bdiv;
  long aoff = (long)z1 * sA1 + (long)z2 * sA2;
  B += (long)z1 * sB1 + (long)z2 * sB2;
  long coff = (long)z1 * sC1 + (long)z2 * sC2;

  __shared__ ushort As[64 * 40];  // [m][k], row stride 40 (80B, 16B-aligned, <=2-way banks)
  __shared__ ushort Bs[64 * 40];  // [n][k]
  int t = threadIdx.x;
  int m0 = blockIdx.y * 64, n0 = blockIdx.x * 64;
  int w = t >> 6, lane = t & 63;
  int wr = (w >> 1) * 32, wc = (w & 1) * 32;
  int fm = lane & 15, koff = (lane >> 4) * 8;

  float4v acc[2][2] = {{{0.f, 0.f, 0.f, 0.f}, {0.f, 0.f, 0.f, 0.f}},
                       {{0.f, 0.f, 0.f, 0.f}, {0.f, 0.f, 0.f, 0.f}}};

  int sm = t >> 2, skq = (t & 3) * 8;   // A-staging / B-Nmajor coords
  int bk = t >> 3, bnq = (t & 7) * 8;   // B-Kmajor coords

  for (int k0 = 0; k0 < K; k0 += 32) {
    // stage A (64 m x 32 k)
    if (ABF16) {
      const ushort* Ab = (const ushort*)Av + aoff;
      *(ushort8*)&As[sm * 40 + skq] =
          *(const ushort8*)&Ab[(long)(m0 + sm) * lda + k0 + skq];
    } else {
      const float* Af = (const float*)Av + aoff;
      const float* ap = &Af[(long)(m0 + sm) * lda + k0 + skq];
      float4 x0 = *(const float4*)ap;
      float4 x1 = *(const float4*)(ap + 4);
      ushort8 v;
      v[0] = f2bf(x0.x); v[1] = f2bf(x0.y); v[2] = f2bf(x0.z); v[3] = f2bf(x0.w);
      v[4] = f2bf(x1.x); v[5] = f2bf(x1.y); v[6] = f2bf(x1.z); v[7] = f2bf(x1.w);
      *(ushort8*)&As[sm * 40 + skq] = v;
    }
    // stage B (64 n x 32 k)
    if (!BKMAJOR) {
      *(ushort8*)&Bs[sm * 40 + skq] =
          *(const ushort8*)&B[(long)(n0 + sm) * ldb + k0 + skq];
    } else {
      ushort8 v = *(const ushort8*)&B[(long)(k0 + bk) * ldb + n0 + bnq];
#pragma unroll
      for (int i = 0; i < 8; ++i) Bs[(bnq + i) * 40 + bk] = v[i];
    }
    __syncthreads();

    short8 a0 = *(const short8*)&As[(wr + fm) * 40 + koff];
    short8 a1 = *(const short8*)&As[(wr + 16 + fm) * 40 + koff];
    short8 b0 = *(const short8*)&Bs[(wc + fm) * 40 + koff];
    short8 b1 = *(const short8*)&Bs[(wc + 16 + fm) * 40 + koff];
    acc[0][0] = __builtin_amdgcn_mfma_f32_16x16x32_bf16(a0, b0, acc[0][0], 0, 0, 0);
    acc[0][1] = __builtin_amdgcn_mfma_f32_16x16x32_bf16(a0, b1, acc[0][1], 0, 0, 0);
    acc[1][0] = __builtin_amdgcn_mfma_f32_16x16x32_bf16(a1, b0, acc[1][0], 0, 0, 0);
    acc[1][1] = __builtin_amdgcn_mfma_f32_16x16x32_bf16(a1, b1, acc[1][1], 0, 0, 0);
    __syncthreads();
  }

  // epilogue: C[row][col], col=lane&15, row=(lane>>4)*4+r  (within each 16x16 frag)
#pragma unroll
  for (int j = 0; j < 2; ++j) {
    int col = n0 + wc + 16 * j + fm;
    float bv = bias ? bias[col] : 0.f;
#pragma unroll
    for (int i = 0; i < 2; ++i) {
#pragma unroll
      for (int r = 0; r < 4; ++r) {
        int row = m0 + wr + 16 * i + (lane >> 4) * 4 + r;
        float v = acc[i][j][r] * alpha + bv;
        if (GELU_) v = 0.5f * v * (1.f + erff(v * 0.7071067811865476f));
        if (CBF16)
          ((ushort*)Cv)[coff + (long)row * ldc + col] = f2bf(v);
        else
          ((float*)Cv)[coff + (long)row * ldc + col] = v;
      }
    }
  }
}

// ---------------- softmax over rows of 512, in place (wave per row) ----------------
__global__ __launch_bounds__(256) void softmax_kernel(float* __restrict__ P) {
  long row = (long)blockIdx.x * 4 + (threadIdx.x >> 6);
  int lane = threadIdx.x & 63;
  float* p = P + row * 512 + lane * 8;
  float4 v0 = *(float4*)p;
  float4 v1 = *(float4*)(p + 4);
  float m = fmaxf(fmaxf(fmaxf(v0.x, v0.y), fmaxf(v0.z, v0.w)),
                  fmaxf(fmaxf(v1.x, v1.y), fmaxf(v1.z, v1.w)));
#pragma unroll
  for (int off = 1; off < 64; off <<= 1) m = fmaxf(m, __shfl_xor(m, off));
  v0.x = __expf(v0.x - m); v0.y = __expf(v0.y - m);
  v0.z = __expf(v0.z - m); v0.w = __expf(v0.w - m);
  v1.x = __expf(v1.x - m); v1.y = __expf(v1.y - m);
  v1.z = __expf(v1.z - m); v1.w = __expf(v1.w - m);
  float s = v0.x + v0.y + v0.z + v0.w + v1.x + v1.y + v1.z + v1.w;
#pragma unroll
  for (int off = 1; off < 64; off <<= 1) s += __shfl_xor(s, off);
  float inv = 1.f / s;
  v0.x *= inv; v0.y *= inv; v0.z *= inv; v0.w *= inv;
  v1.x *= inv; v1.y *= inv; v1.z *= inv; v1.w *= inv;
  *(float4*)p = v0;
  *(float4*)(p + 4) = v1;
}

// ---------------- prior + sigma elementwise ----------------
__global__ __launch_bounds__(256) void prior_kernel(const float* __restrict__ sig,
                                                    float* __restrict__ prior,
                                                    float* __restrict__ sigma4) {
  int blk = blockIdx.x;  // (b*8+h)*512 + i
  int i = blk & 511;
  int bh = blk >> 9;
  int b = bh >> 3, hh = bh & 7;
  float xv = sig[(((long)b << 9) + i) * 8 + hh];
  float s = 1.f / (1.f + expf(-5.f * xv)) + 1e-5f;
  float sg = expm1f(s * 1.0986122886681098f);
  float inv = 0.3989422804014327f / sg;
  float rinv = 1.f / sg;
  long base = ((long)bh << 18) + ((long)i << 9);
  int j0 = threadIdx.x * 2;
  float d0 = fabsf((float)(i - j0));
  float d1 = fabsf((float)(i - (j0 + 1)));
  float r0 = d0 * rinv, r1 = d1 * rinv;
  float2 pv = {inv * expf(-0.5f * r0 * r0), inv * expf(-0.5f * r1 * r1)};
  float2 sv = {sg, sg};
  *(float2*)&prior[base + j0] = pv;
  *(float2*)&sigma4[base + j0] = sv;
}

// ---------------- residual + layernorm ----------------
__global__ __launch_bounds__(256) void ln_kernel(const float* __restrict__ x,
                                                 const float* __restrict__ delta,
                                                 const float* __restrict__ g,
                                                 const float* __restrict__ bb,
                                                 float* __restrict__ out) {
  long row = blockIdx.x;
  int tid = threadIdx.x;
  int c = tid * 2;
  float2 xv = *(const float2*)&x[row * 512 + c];
  if (delta) {
    float2 dv = *(const float2*)&delta[row * 512 + c];
    xv.x += dv.x; xv.y += dv.y;
  }
  float s = xv.x + xv.y;
  float q = xv.x * xv.x + xv.y * xv.y;
#pragma unroll
  for (int off = 1; off < 64; off <<= 1) {
    s += __shfl_xor(s, off);
    q += __shfl_xor(q, off);
  }
  __shared__ float red[8];
  int wid = tid >> 6;
  if ((tid & 63) == 0) { red[wid] = s; red[wid + 4] = q; }
  __syncthreads();
  float S = red[0] + red[1] + red[2] + red[3];
  float Q = red[4] + red[5] + red[6] + red[7];
  float mean = S * (1.f / 512.f);
  float var = Q * (1.f / 512.f) - mean * mean;
  float rstd = rsqrtf(var + 1e-3f);
  float2 o;
  o.x = (xv.x - mean) * rstd * g[c] + bb[c];
  o.y = (xv.y - mean) * rstd * g[c + 1] + bb[c + 1];
  *(float2*)&out[row * 512 + c] = o;
}

// ---------------- small-N GEMM (wave per row), fp32 ----------------
template <int NOUT>
__global__ __launch_bounds__(256) void gemm_smallN(const float* __restrict__ A,
                                                   const float* __restrict__ W,
                                                   const float* __restrict__ bias,
                                                   float* __restrict__ C) {
  long row = (long)blockIdx.x * 4 + (threadIdx.x >> 6);
  int lane = threadIdx.x & 63;
  float acc[NOUT];
#pragma unroll
  for (int j = 0; j < NOUT; ++j) acc[j] = 0.f;
  for (int k = lane; k < 512; k += 64) {
    float a = A[row * 512 + k];
    const float* wr = W + (long)k * NOUT;
#pragma unroll
    for (int j = 0; j < NOUT; ++j) acc[j] = fmaf(a, wr[j], acc[j]);
  }
#pragma unroll
  for (int j = 0; j < NOUT; ++j)
#pragma unroll
    for (int off = 32; off; off >>= 1) acc[j] += __shfl_xor(acc[j], off);
  if (lane == 0) {
#pragma unroll
    for (int j = 0; j < NOUT; ++j) C[row * NOUT + j] = acc[j] + bias[j];
  }
}

extern "C" void kernel_launch(void* const* d_in, const int* in_sizes, int n_in,
                              void* d_out, int out_size, void* d_ws, size_t ws_size,
                              hipStream_t stream) {
  (void)in_sizes; (void)n_in; (void)out_size; (void)ws_size;
  const float* x    = (const float*)d_in[0];
  const float* ck   = (const float*)d_in[1];
  const float* Wq   = (const float*)d_in[2];
  const float* bq   = (const float*)d_in[3];
  const float* Wk   = (const float*)d_in[4];
  const float* bk   = (const float*)d_in[5];
  const float* Wv   = (const float*)d_in[6];
  const float* bv   = (const float*)d_in[7];
  const float* Wsw  = (const float*)d_in[8];
  const float* bsw  = (const float*)d_in[9];
  const float* Wo   = (const float*)d_in[10];
  const float* bo   = (const float*)d_in[11];
  const float* W1   = (const float*)d_in[12];
  const float* b1   = (const float*)d_in[13];
  const float* W2   = (const float*)d_in[14];
  const float* b2   = (const float*)d_in[15];
  const float* ln1g = (const float*)d_in[16];
  const float* ln1b = (const float*)d_in[17];
  const float* ln2g = (const float*)d_in[18];
  const float* ln2b = (const float*)d_in[19];
  const float* lnfg = (const float*)d_in[20];
  const float* lnfb = (const float*)d_in[21];
  const float* Wp   = (const float*)d_in[22];
  const float* bp   = (const float*)d_in[23];
  float* out = (float*)d_out;

  // ws: h,t1,t2 fp32; sg fp32; qb,kb,vb bf16; wt bf16[6*3*512*512]  (~47 MB)
  float* h  = (float*)d_ws;
  float* t1 = h + 2097152;
  float* t2 = t1 + 2097152;
  float* sg = t2 + 2097152;
  ushort* qb = (ushort*)(sg + 32768);
  ushort* kb = qb + 2097152;
  ushort* vb = kb + 2097152;
  ushort* wt = vb + 2097152;

  float* series0 = out + 155648;
  float* prior0  = out + 50487296;
  float* sigma0  = out + 100818944;

  // pre-transpose+convert the 6 weight families (3 layers each) to bf16 [n][k]
  dim3 gW(2, 64, 3);
  wcvt_kernel<<<gW, 256, 0, stream>>>(Wq, wt + 0L * 3 * 262144);
  wcvt_kernel<<<gW, 256, 0, stream>>>(Wk, wt + 1L * 3 * 262144);
  wcvt_kernel<<<gW, 256, 0, stream>>>(Wv, wt + 2L * 3 * 262144);
  wcvt_kernel<<<gW, 256, 0, stream>>>(Wo, wt + 3L * 3 * 262144);
  wcvt_kernel<<<gW, 256, 0, stream>>>(W1, wt + 4L * 3 * 262144);
  wcvt_kernel<<<gW, 256, 0, stream>>>(W2, wt + 5L * 3 * 262144);

  embed_kernel<<<4096, 512, 0, stream>>>(x, ck, h);

  dim3 gFull(8, 64, 1);   // N=512, M=4096
  dim3 gScore(8, 8, 64);  // N=512, M=512, z=(b,h)
  dim3 gAttn(1, 8, 64);   // N=64,  M=512, z=(b,h)

  for (int l = 0; l < 3; ++l) {
    const ushort* wtq = wt + (0L * 3 + l) * 262144;
    const ushort* wtk = wt + (1L * 3 + l) * 262144;
    const ushort* wtv = wt + (2L * 3 + l) * 262144;
    const ushort* wto = wt + (3L * 3 + l) * 262144;
    const ushort* wt1 = wt + (4L * 3 + l) * 262144;
    const ushort* wt2 = wt + (5L * 3 + l) * 262144;
    const float* Ws_l = Wsw + (long)l * 4096;  const float* bs_l = bsw + (long)l * 8;
    float* ser = series0 + (long)l * 16777216;
    float* pri = prior0  + (long)l * 16777216;
    float* sgm = sigma0  + (long)l * 16777216;

    // Q, K, V projections (bf16 out)
    gemm_mfma<false, false, false, true><<<gFull, 256, 0, stream>>>(
        h, 512, 0, 0, wtq, 512, 0, 0, bq + (long)l * 512, qb, 512, 0, 0, 512, 1, 1.f);
    gemm_mfma<false, false, false, true><<<gFull, 256, 0, stream>>>(
        h, 512, 0, 0, wtk, 512, 0, 0, bk + (long)l * 512, kb, 512, 0, 0, 512, 1, 1.f);
    gemm_mfma<false, false, false, true><<<gFull, 256, 0, stream>>>(
        h, 512, 0, 0, wtv, 512, 0, 0, bv + (long)l * 512, vb, 512, 0, 0, 512, 1, 1.f);
    // sigma logits (fp32 — prior is highly sensitive to this path)
    gemm_smallN<8><<<1024, 256, 0, stream>>>(h, Ws_l, bs_l, sg);
    // scores = 0.125 * Q @ K^T -> series region (fp32)
    gemm_mfma<true, false, false, false><<<gScore, 256, 0, stream>>>(
        qb, 512, 262144, 64, kb, 512, 262144, 64, nullptr,
        ser, 512, 2097152, 262144, 64, 8, 0.125f);
    softmax_kernel<<<8192, 256, 0, stream>>>(ser);
    prior_kernel<<<32768, 256, 0, stream>>>(sg, pri, sgm);
    // attn_out = P @ V   (A fp32->bf16 staged; B=V is [s][d] K-major)
    gemm_mfma<false, true, false, false><<<gAttn, 256, 0, stream>>>(
        ser, 512, 2097152, 262144, vb, 512, 262144, 64, nullptr,
        t1, 512, 262144, 64, 512, 8, 1.f);
    // Wo projection
    gemm_mfma<false, false, false, false><<<gFull, 256, 0, stream>>>(
        t1, 512, 0, 0, wto, 512, 0, 0, bo + (long)l * 512, t2, 512, 0, 0, 512, 1, 1.f);
    ln_kernel<<<4096, 256, 0, stream>>>(h, t2, ln1g + l * 512, ln1b + l * 512, h);
    // FF
    gemm_mfma<false, false, true, false><<<gFull, 256, 0, stream>>>(
        h, 512, 0, 0, wt1, 512, 0, 0, b1 + (long)l * 512, t1, 512, 0, 0, 512, 1, 1.f);
    gemm_mfma<false, false, false, false><<<gFull, 256, 0, stream>>>(
        t1, 512, 0, 0, wt2, 512, 0, 0, b2 + (long)l * 512, t2, 512, 0, 0, 512, 1, 1.f);
    ln_kernel<<<4096, 256, 0, stream>>>(h, t2, ln2g + l * 512, ln2b + l * 512, h);
  }

  ln_kernel<<<4096, 256, 0, stream>>>(h, nullptr, lnfg, lnfb, t1);
  gemm_smallN<38><<<1024, 256, 0, stream>>>(t1, Wp, bp, out);
}

// Round 3
// 1083.154 us; speedup vs baseline: 1.6797x; 1.1489x over previous
//
#include <hip/hip_runtime.h>
#include <math.h>

// AnomalyTransformer forward. bf16-MFMA GEMMs (fp32 accumulate).
// Round 3: fused attention kernel (S = QK^T -> softmax -> series write ->
// P@V -> prior/sigma), QKV as one N=1536 GEMM.
// B=8, WIN=512, D=512, H=8, EH=64, L=3, FF=512.
// d_out (f32): out[155648] | series[3*16777216] | prior | sigma

typedef unsigned short ushort;
typedef __attribute__((ext_vector_type(8))) ushort ushort8;
typedef __attribute__((ext_vector_type(8))) short short8;
typedef __attribute__((ext_vector_type(4))) float float4v;

__device__ inline ushort f2bf(float f) {
  union { float f; unsigned u; } v; v.f = f;
  return (ushort)((v.u + 0x7fffu + ((v.u >> 16) & 1u)) >> 16);
}

// ---------------- embed: wrap-pad conv1d(k=3) + sinusoidal PE ----------------
__global__ __launch_bounds__(512) void embed_kernel(const float* __restrict__ x,
                                                    const float* __restrict__ ck,
                                                    float* __restrict__ h) {
  int bt = blockIdx.x;
  int b = bt >> 9, t = bt & 511;
  int co = threadIdx.x;
  __shared__ float xs[3][38];
  if (co < 114) {
    int w = co / 38, ci = co - w * 38;
    int r = (t - 1 + w + 512) & 511;
    xs[w][ci] = x[((long)(b << 9) + r) * 38 + ci];
  }
  __syncthreads();
  float acc = 0.f;
#pragma unroll
  for (int w = 0; w < 3; ++w)
#pragma unroll
    for (int ci = 0; ci < 38; ++ci)
      acc = fmaf(xs[w][ci], ck[(w * 38 + ci) * 512 + co], acc);
  float div = expf((float)(co & ~1) * (-9.210340371976184f / 512.f));
  float ang = (float)t * div;
  float pe = (co & 1) ? cosf(ang) : sinf(ang);
  h[(long)bt * 512 + co] = acc + pe;
}

// ------ weight convert+transpose: fp32 [k][n] -> bf16 [n][k], 3 layers ------
__global__ __launch_bounds__(256) void wcvt_kernel(const float* __restrict__ W,
                                                   ushort* __restrict__ Wt,
                                                   long lstride) {
  int l = blockIdx.z;
  int n = blockIdx.x * 256 + threadIdx.x;
  int k0 = blockIdx.y * 8;
  const float* w = W + (long)l * 262144;
  ushort* o = Wt + (long)l * lstride;
  ushort8 v;
#pragma unroll
  for (int i = 0; i < 8; ++i) v[i] = f2bf(w[(long)(k0 + i) * 512 + n]);
  *(ushort8*)&o[(long)n * 512 + k0] = v;
}

// ---------------- concat q/k/v biases -> [l][1536] ----------------
__global__ __launch_bounds__(512) void bcat_kernel(const float* __restrict__ bq,
                                                   const float* __restrict__ bk,
                                                   const float* __restrict__ bv,
                                                   float* __restrict__ bqkv) {
  int l = blockIdx.x, t = threadIdx.x;
  bqkv[l * 1536 + t] = bq[l * 512 + t];
  bqkv[l * 1536 + 512 + t] = bk[l * 512 + t];
  bqkv[l * 1536 + 1024 + t] = bv[l * 512 + t];
}

// ---------------- bf16 MFMA GEMM: C = alpha*(A@B) (+bias)(+gelu) ----------------
template <bool ABF16, bool GELU_, bool CBF16>
__global__ __launch_bounds__(256) void gemm_mfma(
    const void* __restrict__ Av, int lda,
    const ushort* __restrict__ B, int ldb,
    const float* __restrict__ bias,
    void* __restrict__ Cv, int ldc,
    int K, float alpha) {
  __shared__ ushort As[64 * 40];
  __shared__ ushort Bs[64 * 40];
  int t = threadIdx.x;
  int m0 = blockIdx.y * 64, n0 = blockIdx.x * 64;
  int w = t >> 6, lane = t & 63;
  int wr = (w >> 1) * 32, wc = (w & 1) * 32;
  int fm = lane & 15, koff = (lane >> 4) * 8;

  float4v acc[2][2] = {{{0.f, 0.f, 0.f, 0.f}, {0.f, 0.f, 0.f, 0.f}},
                       {{0.f, 0.f, 0.f, 0.f}, {0.f, 0.f, 0.f, 0.f}}};
  int sm = t >> 2, skq = (t & 3) * 8;

  for (int k0 = 0; k0 < K; k0 += 32) {
    if (ABF16) {
      const ushort* Ab = (const ushort*)Av;
      *(ushort8*)&As[sm * 40 + skq] =
          *(const ushort8*)&Ab[(long)(m0 + sm) * lda + k0 + skq];
    } else {
      const float* Af = (const float*)Av;
      const float* ap = &Af[(long)(m0 + sm) * lda + k0 + skq];
      float4 x0 = *(const float4*)ap;
      float4 x1 = *(const float4*)(ap + 4);
      ushort8 v;
      v[0] = f2bf(x0.x); v[1] = f2bf(x0.y); v[2] = f2bf(x0.z); v[3] = f2bf(x0.w);
      v[4] = f2bf(x1.x); v[5] = f2bf(x1.y); v[6] = f2bf(x1.z); v[7] = f2bf(x1.w);
      *(ushort8*)&As[sm * 40 + skq] = v;
    }
    *(ushort8*)&Bs[sm * 40 + skq] =
        *(const ushort8*)&B[(long)(n0 + sm) * ldb + k0 + skq];
    __syncthreads();

    short8 a0 = *(const short8*)&As[(wr + fm) * 40 + koff];
    short8 a1 = *(const short8*)&As[(wr + 16 + fm) * 40 + koff];
    short8 b0 = *(const short8*)&Bs[(wc + fm) * 40 + koff];
    short8 b1 = *(const short8*)&Bs[(wc + 16 + fm) * 40 + koff];
    acc[0][0] = __builtin_amdgcn_mfma_f32_16x16x32_bf16(a0, b0, acc[0][0], 0, 0, 0);
    acc[0][1] = __builtin_amdgcn_mfma_f32_16x16x32_bf16(a0, b1, acc[0][1], 0, 0, 0);
    acc[1][0] = __builtin_amdgcn_mfma_f32_16x16x32_bf16(a1, b0, acc[1][0], 0, 0, 0);
    acc[1][1] = __builtin_amdgcn_mfma_f32_16x16x32_bf16(a1, b1, acc[1][1], 0, 0, 0);
    __syncthreads();
  }

#pragma unroll
  for (int j = 0; j < 2; ++j) {
    int col = n0 + wc + 16 * j + fm;
    float bv = bias ? bias[col] : 0.f;
#pragma unroll
    for (int i = 0; i < 2; ++i) {
#pragma unroll
      for (int r = 0; r < 4; ++r) {
        int row = m0 + wr + 16 * i + (lane >> 4) * 4 + r;
        float v = acc[i][j][r] * alpha + bv;
        if (GELU_) v = 0.5f * v * (1.f + erff(v * 0.7071067811865476f));
        if (CBF16)
          ((ushort*)Cv)[(long)row * ldc + col] = f2bf(v);
        else
          ((float*)Cv)[(long)row * ldc + col] = v;
      }
    }
  }
}

// ---------------- fused attention ----------------
// grid (8 mtiles, 64 bh), 256 threads (4 waves).
// qkv bf16 [4096][1536] (q | k | v). Computes for rows m0..m0+63, head h:
//   S = Q K^T * 0.125 -> softmax -> series (fp32, global) and Ps (bf16, LDS)
//   O = P @ V -> t1 ;  prior/sigma from sg.
__global__ __launch_bounds__(256, 1) void attn_fused(
    const ushort* __restrict__ qkv, const float* __restrict__ sg,
    float* __restrict__ series, float* __restrict__ prior,
    float* __restrict__ sigma, float* __restrict__ t1) {
  __shared__ ushort KPs[36864];  // K [512][72] bf16, later Ps [64][520] bf16
  __shared__ ushort Qs[4608];    // Q [64][72]
  __shared__ ushort Vc[4608];    // V-chunk transposed [64 d][72 s]
  __shared__ float red[256];     // softmax cross-wave scratch / sigma row consts

  int t = threadIdx.x;
  int m0 = blockIdx.x * 64;
  int bh = blockIdx.y;
  int b = bh >> 3, hh = bh & 7;
  int w = t >> 6, lane = t & 63;
  int fm = lane & 15, q4 = lane >> 4;
  int wc = w * 128;
  long rowg = (long)b * 512;

  // ---- stage Q (64x64) and K (512x64) ----
  {
    int row = t >> 2, kq = (t & 3) * 16;
    const ushort* src = &qkv[(rowg + m0 + row) * 1536 + hh * 64 + kq];
    *(ushort8*)&Qs[row * 72 + kq] = *(const ushort8*)src;
    *(ushort8*)&Qs[row * 72 + kq + 8] = *(const ushort8*)(src + 8);
#pragma unroll
    for (int p = 0; p < 8; ++p) {
      int srow = p * 64 + row;
      const ushort* ks = &qkv[(rowg + srow) * 1536 + 512 + hh * 64 + kq];
      *(ushort8*)&KPs[srow * 72 + kq] = *(const ushort8*)ks;
      *(ushort8*)&KPs[srow * 72 + kq + 8] = *(const ushort8*)(ks + 8);
    }
  }
  __syncthreads();

  // ---- S = Q @ K^T : acc[i=mfrag 0..3][j=nfrag 0..7] ----
  float4v acc[4][8];
#pragma unroll
  for (int i = 0; i < 4; ++i)
#pragma unroll
    for (int j = 0; j < 8; ++j) acc[i][j] = (float4v){0.f, 0.f, 0.f, 0.f};

#pragma unroll
  for (int ks = 0; ks < 2; ++ks) {
    int ko = ks * 32 + q4 * 8;
    short8 a[4], bfr[8];
#pragma unroll
    for (int i = 0; i < 4; ++i)
      a[i] = *(const short8*)&Qs[(16 * i + fm) * 72 + ko];
#pragma unroll
    for (int j = 0; j < 8; ++j)
      bfr[j] = *(const short8*)&KPs[(wc + 16 * j + fm) * 72 + ko];
#pragma unroll
    for (int i = 0; i < 4; ++i)
#pragma unroll
      for (int j = 0; j < 8; ++j)
        acc[i][j] = __builtin_amdgcn_mfma_f32_16x16x32_bf16(a[i], bfr[j], acc[i][j], 0, 0, 0);
  }

  // ---- softmax over full rows (512 cols per row) ----
  // C layout: row = 16i + q4*4 + r, col = wc + 16j + fm.
#pragma unroll
  for (int i = 0; i < 4; ++i)
#pragma unroll
    for (int j = 0; j < 8; ++j)
#pragma unroll
      for (int r = 0; r < 4; ++r) acc[i][j][r] *= 0.125f;

  float mrow[4][4];
#pragma unroll
  for (int i = 0; i < 4; ++i)
#pragma unroll
    for (int r = 0; r < 4; ++r) {
      float m = acc[i][0][r];
#pragma unroll
      for (int j = 1; j < 8; ++j) m = fmaxf(m, acc[i][j][r]);
#pragma unroll
      for (int off = 1; off < 16; off <<= 1) m = fmaxf(m, __shfl_xor(m, off));
      mrow[i][r] = m;
    }
  if (fm == 0) {
#pragma unroll
    for (int i = 0; i < 4; ++i)
#pragma unroll
      for (int r = 0; r < 4; ++r)
        red[(16 * i + q4 * 4 + r) * 4 + w] = mrow[i][r];
  }
  __syncthreads();
#pragma unroll
  for (int i = 0; i < 4; ++i)
#pragma unroll
    for (int r = 0; r < 4; ++r) {
      const float* rp = &red[(16 * i + q4 * 4 + r) * 4];
      mrow[i][r] = fmaxf(fmaxf(rp[0], rp[1]), fmaxf(rp[2], rp[3]));
    }
  float lrow[4][4];
#pragma unroll
  for (int i = 0; i < 4; ++i)
#pragma unroll
    for (int r = 0; r < 4; ++r) {
      float s = 0.f;
#pragma unroll
      for (int j = 0; j < 8; ++j) {
        float e = __expf(acc[i][j][r] - mrow[i][r]);
        acc[i][j][r] = e;
        s += e;
      }
#pragma unroll
      for (int off = 1; off < 16; off <<= 1) s += __shfl_xor(s, off);
      lrow[i][r] = s;
    }
  __syncthreads();  // all waves done reading red(max)
  if (fm == 0) {
#pragma unroll
    for (int i = 0; i < 4; ++i)
#pragma unroll
      for (int r = 0; r < 4; ++r)
        red[(16 * i + q4 * 4 + r) * 4 + w] = lrow[i][r];
  }
  __syncthreads();
#pragma unroll
  for (int i = 0; i < 4; ++i)
#pragma unroll
    for (int r = 0; r < 4; ++r) {
      const float* rp = &red[(16 * i + q4 * 4 + r) * 4];
      lrow[i][r] = 1.f / (rp[0] + rp[1] + rp[2] + rp[3]);
    }

  // ---- write series (fp32 global) + Ps (bf16 LDS, overwrites K region) ----
  float* serp = series + ((long)bh << 18);
#pragma unroll
  for (int i = 0; i < 4; ++i)
#pragma unroll
    for (int r = 0; r < 4; ++r) {
      int row = 16 * i + q4 * 4 + r;
      float inv = lrow[i][r];
#pragma unroll
      for (int j = 0; j < 8; ++j) {
        int col = wc + 16 * j + fm;
        float v = acc[i][j][r] * inv;
        serp[(long)(m0 + row) * 512 + col] = v;
        KPs[row * 520 + col] = f2bf(v);
      }
    }

  // ---- O = P @ V  (stream V in 8 transposed chunks) ----
  float4v acc2[4] = {{0.f, 0.f, 0.f, 0.f}, {0.f, 0.f, 0.f, 0.f},
                     {0.f, 0.f, 0.f, 0.f}, {0.f, 0.f, 0.f, 0.f}};
  int wn = w * 16;
  int s_local = t >> 2, cgrp = (t & 3) * 16;
  for (int c = 0; c < 8; ++c) {
    __syncthreads();  // protect Vc (and first-iter Ps writes)
    const ushort* vs = &qkv[(rowg + c * 64 + s_local) * 1536 + 1024 + hh * 64 + cgrp];
    ushort8 v0 = *(const ushort8*)vs;
    ushort8 v1 = *(const ushort8*)(vs + 8);
#pragma unroll
    for (int e = 0; e < 8; ++e) {
      Vc[(cgrp + e) * 72 + s_local] = v0[e];
      Vc[(cgrp + 8 + e) * 72 + s_local] = v1[e];
    }
    __syncthreads();
#pragma unroll
    for (int ks = 0; ks < 2; ++ks) {
      int ko = ks * 32 + q4 * 8;
      short8 b2 = *(const short8*)&Vc[(wn + fm) * 72 + ko];
#pragma unroll
      for (int i = 0; i < 4; ++i) {
        short8 a2 = *(const short8*)&KPs[(16 * i + fm) * 520 + c * 64 + ko];
        acc2[i] = __builtin_amdgcn_mfma_f32_16x16x32_bf16(a2, b2, acc2[i], 0, 0, 0);
      }
    }
  }
#pragma unroll
  for (int i = 0; i < 4; ++i)
#pragma unroll
    for (int r = 0; r < 4; ++r)
      t1[(rowg + m0 + 16 * i + q4 * 4 + r) * 512 + hh * 64 + wn + fm] = acc2[i][r];

  // ---- prior + sigma for rows m0..m0+63 ----
  __syncthreads();
  if (t < 64) {
    float xv = sg[(rowg + m0 + t) * 8 + hh];
    float s = 1.f / (1.f + __expf(-5.f * xv)) + 1e-5f;
    float sgv = expm1f(s * 1.0986122886681098f);
    red[t * 3] = sgv;
    red[t * 3 + 1] = 0.3989422804014327f / sgv;
    red[t * 3 + 2] = 1.f / sgv;
  }
  __syncthreads();
  float* prip = prior + ((long)bh << 18);
  float* sigp = sigma + ((long)bh << 18);
  for (int it = t; it < 8192; it += 256) {
    int row = it >> 7;
    int c4 = (it & 127) << 2;
    float sgv = red[row * 3], inv = red[row * 3 + 1], rinv = red[row * 3 + 2];
    float ig = (float)(m0 + row);
    float4 pv, sv;
#pragma unroll
    for (int e = 0; e < 4; ++e) {
      float dd = ig - (float)(c4 + e);
      float rr = dd * rinv;
      ((float*)&pv)[e] = inv * __expf(-0.5f * rr * rr);
      ((float*)&sv)[e] = sgv;
    }
    *(float4*)&prip[(long)(m0 + row) * 512 + c4] = pv;
    *(float4*)&sigp[(long)(m0 + row) * 512 + c4] = sv;
  }
}

// ---------------- residual + layernorm ----------------
__global__ __launch_bounds__(256) void ln_kernel(const float* __restrict__ x,
                                                 const float* __restrict__ delta,
                                                 const float* __restrict__ g,
                                                 const float* __restrict__ bb,
                                                 float* __restrict__ out) {
  long row = blockIdx.x;
  int tid = threadIdx.x;
  int c = tid * 2;
  float2 xv = *(const float2*)&x[row * 512 + c];
  if (delta) {
    float2 dv = *(const float2*)&delta[row * 512 + c];
    xv.x += dv.x; xv.y += dv.y;
  }
  float s = xv.x + xv.y;
  float q = xv.x * xv.x + xv.y * xv.y;
#pragma unroll
  for (int off = 1; off < 64; off <<= 1) {
    s += __shfl_xor(s, off);
    q += __shfl_xor(q, off);
  }
  __shared__ float red[8];
  int wid = tid >> 6;
  if ((tid & 63) == 0) { red[wid] = s; red[wid + 4] = q; }
  __syncthreads();
  float S = red[0] + red[1] + red[2] + red[3];
  float Q = red[4] + red[5] + red[6] + red[7];
  float mean = S * (1.f / 512.f);
  float var = Q * (1.f / 512.f) - mean * mean;
  float rstd = rsqrtf(var + 1e-3f);
  float2 o;
  o.x = (xv.x - mean) * rstd * g[c] + bb[c];
  o.y = (xv.y - mean) * rstd * g[c + 1] + bb[c + 1];
  *(float2*)&out[row * 512 + c] = o;
}

// ---------------- small-N GEMM (wave per row), fp32 ----------------
template <int NOUT>
__global__ __launch_bounds__(256) void gemm_smallN(const float* __restrict__ A,
                                                   const float* __restrict__ W,
                                                   const float* __restrict__ bias,
                                                   float* __restrict__ C) {
  long row = (long)blockIdx.x * 4 + (threadIdx.x >> 6);
  int lane = threadIdx.x & 63;
  float acc[NOUT];
#pragma unroll
  for (int j = 0; j < NOUT; ++j) acc[j] = 0.f;
  for (int k = lane; k < 512; k += 64) {
    float a = A[row * 512 + k];
    const float* wr = W + (long)k * NOUT;
#pragma unroll
    for (int j = 0; j < NOUT; ++j) acc[j] = fmaf(a, wr[j], acc[j]);
  }
#pragma unroll
  for (int j = 0; j < NOUT; ++j)
#pragma unroll
    for (int off = 32; off; off >>= 1) acc[j] += __shfl_xor(acc[j], off);
  if (lane == 0) {
#pragma unroll
    for (int j = 0; j < NOUT; ++j) C[row * NOUT + j] = acc[j] + bias[j];
  }
}

extern "C" void kernel_launch(void* const* d_in, const int* in_sizes, int n_in,
                              void* d_out, int out_size, void* d_ws, size_t ws_size,
                              hipStream_t stream) {
  (void)in_sizes; (void)n_in; (void)out_size; (void)ws_size;
  const float* x    = (const float*)d_in[0];
  const float* ck   = (const float*)d_in[1];
  const float* Wq   = (const float*)d_in[2];
  const float* bq   = (const float*)d_in[3];
  const float* Wk   = (const float*)d_in[4];
  const float* bk   = (const float*)d_in[5];
  const float* Wv   = (const float*)d_in[6];
  const float* bv   = (const float*)d_in[7];
  const float* Wsw  = (const float*)d_in[8];
  const float* bsw  = (const float*)d_in[9];
  const float* Wo   = (const float*)d_in[10];
  const float* bo   = (const float*)d_in[11];
  const float* W1   = (const float*)d_in[12];
  const float* b1   = (const float*)d_in[13];
  const float* W2   = (const float*)d_in[14];
  const float* b2   = (const float*)d_in[15];
  const float* ln1g = (const float*)d_in[16];
  const float* ln1b = (const float*)d_in[17];
  const float* ln2g = (const float*)d_in[18];
  const float* ln2b = (const float*)d_in[19];
  const float* lnfg = (const float*)d_in[20];
  const float* lnfb = (const float*)d_in[21];
  const float* Wp   = (const float*)d_in[22];
  const float* bp   = (const float*)d_in[23];
  float* out = (float*)d_out;

  // ws layout
  float* h    = (float*)d_ws;
  float* t1   = h + 2097152;
  float* t2   = t1 + 2097152;
  float* sg   = t2 + 2097152;           // 32768
  float* bqkv = sg + 32768;             // 4608
  ushort* qkv  = (ushort*)(bqkv + 4608);        // 4096*1536
  ushort* wqkv = qkv + 6291456;                 // 3*1536*512
  ushort* wo3  = wqkv + 2359296;                // 3*512*512
  ushort* w13  = wo3 + 786432;
  ushort* w23  = w13 + 786432;

  float* series0 = out + 155648;
  float* prior0  = out + 50487296;
  float* sigma0  = out + 100818944;

  dim3 gW(2, 64, 3);
  wcvt_kernel<<<gW, 256, 0, stream>>>(Wq, wqkv, 786432);
  wcvt_kernel<<<gW, 256, 0, stream>>>(Wk, wqkv + 262144, 786432);
  wcvt_kernel<<<gW, 256, 0, stream>>>(Wv, wqkv + 524288, 786432);
  wcvt_kernel<<<gW, 256, 0, stream>>>(Wo, wo3, 262144);
  wcvt_kernel<<<gW, 256, 0, stream>>>(W1, w13, 262144);
  wcvt_kernel<<<gW, 256, 0, stream>>>(W2, w23, 262144);
  bcat_kernel<<<3, 512, 0, stream>>>(bq, bk, bv, bqkv);

  embed_kernel<<<4096, 512, 0, stream>>>(x, ck, h);

  dim3 gQKV(24, 64, 1);   // N=1536, M=4096
  dim3 gFull(8, 64, 1);   // N=512, M=4096
  dim3 gAttn(8, 64, 1);   // 8 mtiles x 64 bh

  for (int l = 0; l < 3; ++l) {
    float* ser = series0 + (long)l * 16777216;
    float* pri = prior0  + (long)l * 16777216;
    float* sgm = sigma0  + (long)l * 16777216;

    // fused QKV projection -> qkv bf16 [4096][1536]
    gemm_mfma<false, false, true><<<gQKV, 256, 0, stream>>>(
        h, 512, wqkv + (long)l * 786432, 512, bqkv + l * 1536, qkv, 1536, 512, 1.f);
    // sigma logits (fp32)
    gemm_smallN<8><<<1024, 256, 0, stream>>>(h, Wsw + (long)l * 4096, bsw + l * 8, sg);
    // fused attention: series/prior/sigma + attn-out (t1)
    attn_fused<<<gAttn, 256, 0, stream>>>(qkv, sg, ser, pri, sgm, t1);
    // Wo projection
    gemm_mfma<false, false, false><<<gFull, 256, 0, stream>>>(
        t1, 512, wo3 + (long)l * 262144, 512, bo + (long)l * 512, t2, 512, 512, 1.f);
    ln_kernel<<<4096, 256, 0, stream>>>(h, t2, ln1g + l * 512, ln1b + l * 512, h);
    // FF
    gemm_mfma<false, true, false><<<gFull, 256, 0, stream>>>(
        h, 512, w13 + (long)l * 262144, 512, b1 + (long)l * 512, t1, 512, 512, 1.f);
    gemm_mfma<false, false, false><<<gFull, 256, 0, stream>>>(
        t1, 512, w23 + (long)l * 262144, 512, b2 + (long)l * 512, t2, 512, 512, 1.f);
    ln_kernel<<<4096, 256, 0, stream>>>(h, t2, ln2g + l * 512, ln2b + l * 512, h);
  }

  ln_kernel<<<4096, 256, 0, stream>>>(h, nullptr, lnfg, lnfb, t1);
  gemm_smallN<38><<<1024, 256, 0, stream>>>(t1, Wp, bp, out);
}